// Round 13
// baseline (273.764 us; speedup 1.0000x reference)
//
#include <hip/hip_runtime.h>
#include <math.h>

// Problem constants (fixed by setup_inputs)
constexpr int K_ = 4, B_ = 8, T_ = 800, C_ = 80, S_ = 128, Z_ = 32;
constexpr int KB_ = K_ * B_;        // 32
constexpr int TC_ = T_ * C_;        // 64000

#define BIGV   1e8f
#define WARP_V 256.0f

// R13 sheared-stream layout, QUAD-MAJOR permutation of R12:
//   Q[u][q][l][e] at float offset u*800 + 200q + 4l + e  =  D[16l+4q+e][u - (i>>3)]
// (g=8 shear: row i's column at step u is j = u - (i>>3); lane l, l=0..49.)
// DP load q has 16B lane stride -> 4 lanes/cache line, ~13 lines/inst
// (vs 64B stride / ~52 lines/inst in R12 -> the R12 TCP wall).
constexpr int NU_   = 900;            // u = j + (i>>3) <= 799 + 99 = 898
constexpr int SLAB_ = NU_ * 800;      // 720,000 floats per problem (92.16 MB total)

__device__ __forceinline__ float sigmoidf_(float v) {
    return 1.f / (1.f + __expf(-v));
}

// ---------------------------------------------------------------- fill j = -1 ghost cells with BIG
// Lanes l<=11 read D[i][-1] (i in [8,191]) at their first step: must be BIG.
__global__ void fill_edge(float* __restrict__ Dm) {
    int kb = blockIdx.x;
    int t = threadIdx.x;
    if (t < 184) {
        int i = 8 + t;     // i in [8, 191]
        size_t off = (size_t)((i >> 3) - 1) * 800 + 200 * ((i >> 2) & 3) + 4 * (i >> 4) + (i & 3);
        Dm[(size_t)kb * SLAB_ + off] = BIGV;
    }
}

// ---------------------------------------------------------------- banded GEMM -> sheared quad-major Q (norms fused)
// grid (5, 13, 32): tiles |ti-tj| <= 2 (written band deviation >= 128 > DP corridor 124).
// Epilogue: LDS shear-transpose -> permuted u-row stores (4 x 64B chunks per inst).
__global__ __launch_bounds__(256) void gemm_band(const float* __restrict__ mel_iters,
                                                 const float* __restrict__ mel_targets,
                                                 float* __restrict__ Dm) {
    const int kb = blockIdx.z;
    const int b  = kb & 7;
    const int ti = blockIdx.y;
    const int tj = ti + (int)blockIdx.x - 2;
    if ((unsigned)tj > 12u) return;

    const float* __restrict__ Xb = mel_iters + (size_t)kb * TC_;
    const float* __restrict__ Yb = mel_targets + (size_t)b * TC_;

    __shared__ float smem[4615];            // phase1: xa[16][68] | ya[16][68] | x2s[64] | y2s[64]
    float (*xa)[68] = (float(*)[68])smem;   // phase2: Zt[71][65]
    float (*ya)[68] = (float(*)[68])(smem + 1088);
    float* x2s = smem + 2176;
    float* y2s = smem + 2240;

    const int tid = threadIdx.x;
    const int tx = tid & 15, ty = tid >> 4;
    const int i0 = ti * 64, j0 = tj * 64;
    const int lr = tid >> 4;   // 0..15
    const int lc = tid & 15;   // 0..15  (k within chunk)

    float acc[4][4] = {};
    float nsum = 0.f;          // row-norm partial (tid<64: x2 row tid; tid in [64,128): y2)

    for (int kk = 0; kk < C_; kk += 16) {
        __syncthreads();
        #pragma unroll
        for (int q = 0; q < 4; ++q) {
            int row = lr + q * 16;       // 0..63
            int gi = i0 + row;
            xa[lc][row] = (gi < T_) ? sigmoidf_(Xb[(size_t)gi * C_ + kk + lc]) : 0.f;
            int gj = j0 + row;
            ya[lc][row] = (gj < T_) ? sigmoidf_(Yb[(size_t)gj * C_ + kk + lc]) : 0.f;
        }
        __syncthreads();
        if (tid < 64) {
            #pragma unroll
            for (int k = 0; k < 16; ++k) { float v = xa[k][tid]; nsum += v * v; }
        } else if (tid < 128) {
            #pragma unroll
            for (int k = 0; k < 16; ++k) { float v = ya[k][tid - 64]; nsum += v * v; }
        }
        #pragma unroll
        for (int k = 0; k < 16; ++k) {
            float4 av = *(const float4*)&xa[k][ty * 4];
            float4 bv = *(const float4*)&ya[k][tx * 4];
            acc[0][0] += av.x * bv.x; acc[0][1] += av.x * bv.y; acc[0][2] += av.x * bv.z; acc[0][3] += av.x * bv.w;
            acc[1][0] += av.y * bv.x; acc[1][1] += av.y * bv.y; acc[1][2] += av.y * bv.z; acc[1][3] += av.y * bv.w;
            acc[2][0] += av.z * bv.x; acc[2][1] += av.z * bv.y; acc[2][2] += av.z * bv.z; acc[2][3] += av.z * bv.w;
            acc[3][0] += av.w * bv.x; acc[3][1] += av.w * bv.y; acc[3][2] += av.w * bv.z; acc[3][3] += av.w * bv.w;
        }
    }
    if (tid < 64) x2s[tid] = nsum;
    else if (tid < 128) y2s[tid - 64] = nsum;
    __syncthreads();

    // read norms into regs BEFORE LDS reuse
    float xs2[4], ys2[4];
    #pragma unroll
    for (int r = 0; r < 4; ++r) xs2[r] = x2s[ty * 4 + r];
    #pragma unroll
    for (int c = 0; c < 4; ++c) ys2[c] = y2s[tx * 4 + c];
    __syncthreads();

    // stage into sheared LDS tile: Zt[u_rel][iLoc], u_rel = 4tx + c + (iLoc>>3)
    float* Zt = smem;                     // [71][65]
    const int sb = ty >> 1;
    #pragma unroll
    for (int r = 0; r < 4; ++r)
        #pragma unroll
        for (int c = 0; c < 4; ++c)
            Zt[(4 * tx + c + sb) * 65 + (4 * ty + r)] = xs2[r] + ys2[c] - 2.f * acc[r][c];
    __syncthreads();

    // permuted u-row stores: u_global = j0 + 8ti + w.
    // lane v writes tile-row rho(v) = 16*((v>>2)&3) + 4*(v>>4) + (v&3)
    // to offset 200*(v>>4) + 4*(4ti + ((v>>2)&3)) + (v&3)  (16-lane groups 64B-contiguous)
    const int w0 = tid >> 6;              // wave id 0..3
    const int lane = tid & 63;
    const int rho = 16 * ((lane >> 2) & 3) + 4 * (lane >> 4) + (lane & 3);
    const int iGlob = i0 + rho;
    const int sbl = rho >> 3;             // s(i) - 8ti
    const bool iok = iGlob < T_;
    const int lofsw = 200 * (lane >> 4) + 4 * (4 * ti + ((lane >> 2) & 3)) + (lane & 3);
    const size_t ub = (size_t)(j0 + 8 * ti) * 800 + lofsw;
    #pragma unroll
    for (int it = 0; it < 18; ++it) {
        int w = w0 + it * 4;
        if (w > 70) break;
        int jrel = w - sbl;
        if (iok && (unsigned)jrel < 64u && (j0 + jrel) < T_)
            Dm[(size_t)kb * SLAB_ + ub + (size_t)w * 800] = Zt[w * 65 + rho];
    }
}

// ---------------------------------------------------------------- single-wave hard-min DTW, r=16, g=8 shear
// One wave per problem: zero barriers/LDS. Lane l rows 16l..16l+15 in two
// independent 8-chains per step (group-1 inputs = S7 history regs).
// R13: quad-major loads -> 16B lane stride, ~13 lines/inst (TCP fix).
__device__ __forceinline__ float wave_shr1(float x) {
    int v = __builtin_amdgcn_update_dpp(0, __float_as_int(x), 0x138, 0xf, 0xf, true);
    return __int_as_float(v);
}

__global__ __launch_bounds__(64, 1) void dtw_wave_kernel(const float* __restrict__ Dm,
                                                         float* __restrict__ dtwv) {
    const int kb = blockIdx.x;
    const int l  = threadIdx.x;
    const int lc = l < 49 ? l : 49;             // lanes 50-63 mirror lane 49
    const bool is_l0 = (l == 0);
    const float* __restrict__ Dd = Dm + (size_t)kb * SLAB_;

    const int ti_l = lc >> 2;
    const int Jlo = ti_l >= 2 ? 64 * (ti_l - 2) : 0;
    const int Jhi = min(799, 64 * ti_l + 191);
    const int lo_u = (Jlo == 0) ? (2 * lc) : (Jlo + 2 * lc + 1);
    const int hi_u = Jhi + 2 * lc + 1;
    const int lofs = lc << 2;                   // 4*l within each 200-float quad block

    // DP state
    float s0 = BIGV, s1 = BIGV, s2 = BIGV, s3 = BIGV, s4 = BIGV, s5 = BIGV, s6 = BIGV, s7 = BIGV;
    float s8 = BIGV, s9 = BIGV, s10 = BIGV, s11 = BIGV, s12 = BIGV, s13 = BIGV, s14 = BIGV, s15 = BIGV;
    float s7p = BIGV;                           // S7 two steps ago
    float tinA = BIGV;                          // lane l-1 S15, one step ago
    float tinB = is_l0 ? 0.f : BIGV;            // two steps ago (lane0: diag of (0,0))

    auto load_batch = [&](float4 (&buf)[4][4], int ub) {
        #pragma unroll
        for (int j = 0; j < 4; ++j) {
            int uc = ub + j;
            uc = uc < lo_u ? lo_u : (uc > hi_u ? hi_u : uc);
            const float* p = Dd + (size_t)uc * 800 + lofs;
            buf[j][0] = *(const float4*)(p);           // rows 16l+0..3   (q=0)
            buf[j][1] = *(const float4*)(p + 200);     // rows 16l+4..7   (q=1)
            buf[j][2] = *(const float4*)(p + 400);     // rows 16l+8..11  (q=2)
            buf[j][3] = *(const float4*)(p + 600);     // rows 16l+12..15 (q=3)
        }
    };

    auto step = [&](const float4 (&dq)[4]) {
        float up8v = s7;                        // S7 after step u-1 (pre-update)
        float dg8v = s7p;                       // S7 after step u-2
        float dgv0 = tinB, upv0 = tinA;
        float dgv1 = dg8v, upv1 = up8v;
        #define CELL2(SA, DA, SB, DB)                                             \
        {   float oA = SA; float wA = (DA) + WARP_V;                              \
            float nA = fminf(fminf(dgv0 + (DA), upv0 + wA), oA + wA);             \
            dgv0 = oA; upv0 = nA; SA = nA;                                        \
            float oB = SB; float wB = (DB) + WARP_V;                              \
            float nB = fminf(fminf(dgv1 + (DB), upv1 + wB), oB + wB);             \
            dgv1 = oB; upv1 = nB; SB = nB;                                        \
        }
        CELL2(s0, dq[0].x, s8,  dq[2].x);
        CELL2(s1, dq[0].y, s9,  dq[2].y);
        CELL2(s2, dq[0].z, s10, dq[2].z);
        CELL2(s3, dq[0].w, s11, dq[2].w);
        CELL2(s4, dq[1].x, s12, dq[3].x);
        CELL2(s5, dq[1].y, s13, dq[3].y);
        CELL2(s6, dq[1].z, s14, dq[3].z);
        CELL2(s7, dq[1].w, s15, dq[3].w);
        #undef CELL2
        s7p = up8v;
        float hand = wave_shr1(s15);
        tinB = tinA;
        tinA = is_l0 ? BIGV : hand;
    };

    auto run4 = [&](const float4 (&buf)[4][4]) {
        #pragma unroll
        for (int j = 0; j < 4; ++j) step(buf[j]);
    };

    float4 bufA[4][4], bufB[4][4], bufC[4][4];
    load_batch(bufA, 0);
    load_batch(bufB, 4);

    int u = 0;
    for (int g = 0; g < 74; ++g) {       // batches 0..221, steps 0..887
        load_batch(bufC, u + 8);
        asm volatile("s_waitcnt vmcnt(32)" ::: "memory");
        run4(bufA);
        u += 4;
        load_batch(bufA, u + 8);
        asm volatile("s_waitcnt vmcnt(32)" ::: "memory");
        run4(bufB);
        u += 4;
        load_batch(bufB, u + 8);
        asm volatile("s_waitcnt vmcnt(32)" ::: "memory");
        run4(bufC);
        u += 4;
    }
    // u = 888: A = 888..891, B = 892..895
    load_batch(bufC, 896);
    asm volatile("s_waitcnt vmcnt(32)" ::: "memory");
    run4(bufA);                                         // 888..891
    asm volatile("s_waitcnt vmcnt(16)" ::: "memory");
    run4(bufB);                                         // 892..895
    asm volatile("s_waitcnt vmcnt(0)" ::: "memory");
    step(bufC[0]);                                      // 896
    step(bufC[1]);                                      // 897
    step(bufC[2]);                                      // 898: lane 49 s15 = R[800][800]

    if (l == 49) dtwv[kb] = s15;
}

// ---------------------------------------------------------------- finalize (scalars)
__global__ void finalize_kernel(const float* __restrict__ dtwv, const int* __restrict__ mel_lens,
                                const int* __restrict__ src_lens, const float* __restrict__ durations,
                                const float* __restrict__ mus, const float* __restrict__ log_vars,
                                const int* __restrict__ step, float* __restrict__ out) {
    const int lane = threadIdx.x;  // 64 threads, one wave

    float v = (lane < KB_) ? dtwv[lane] : 0.f;
    for (int o = 32; o; o >>= 1) v += __shfl_down(v, o);

    float w = (lane < B_) ? 1.f / (K_ * (float)mel_lens[lane]) : 0.f;
    for (int o = 32; o; o >>= 1) w += __shfl_down(w, o);

    float du = 0.f;
    if (lane < B_) {
        float s = 0.f;
        for (int j = 0; j < S_; ++j) s += durations[lane * S_ + j];
        du = fabsf(s - (float)mel_lens[lane]) / (float)src_lens[lane];
    }
    for (int o = 32; o; o >>= 1) du += __shfl_down(du, o);

    float kl = 0.f;
    for (int j = lane; j < B_ * Z_; j += 64) {
        float muv = mus[j], lv = log_vars[j];
        kl += 1.f + lv - muv * muv - expf(lv);
    }
    for (int o = 32; o; o >>= 1) kl += __shfl_down(kl, o);

    if (lane == 0) {
        float mel_iter_loss = v / (float)B_;
        float mel_loss = mel_iter_loss * (w / (float)B_);
        float dur_loss = 2.0f * du / (float)B_;
        float kl_loss = -0.5f * kl;
        int st = step[0];
        float beta = (st < 2000) ? 0.f : ((st >= 8000) ? 1.f : (float)(st - 2000) / 6000.f);
        out[0] = mel_loss + dur_loss + beta * kl_loss;
        out[1] = mel_loss;
        out[2] = dur_loss;
        out[3] = kl_loss;
        out[4] = beta;
    }
}

// ---------------------------------------------------------------- launch
extern "C" void kernel_launch(void* const* d_in, const int* in_sizes, int n_in,
                              void* d_out, int out_size, void* d_ws, size_t ws_size,
                              hipStream_t stream) {
    const float* mel_iters   = (const float*)d_in[0];
    const float* mel_targets = (const float*)d_in[1];
    const int*   mel_lens    = (const int*)d_in[2];
    const int*   src_lens    = (const int*)d_in[3];
    const float* durations   = (const float*)d_in[4];
    const float* mus         = (const float*)d_in[5];
    const float* log_vars    = (const float*)d_in[6];
    const int*   step        = (const int*)d_in[7];
    float* out = (float*)d_out;

    float* ws   = (float*)d_ws;
    float* Dm   = ws;                              // 32 * 720,000 floats = 92.16 MB
    float* dtwv = Dm + (size_t)KB_ * SLAB_;        //        32

    fill_edge<<<KB_, 192, 0, stream>>>(Dm);

    gemm_band<<<dim3(5, 13, KB_), 256, 0, stream>>>(mel_iters, mel_targets, Dm);

    dtw_wave_kernel<<<KB_, 64, 0, stream>>>(Dm, dtwv);

    finalize_kernel<<<1, 64, 0, stream>>>(dtwv, mel_lens, src_lens, durations, mus, log_vars, step, out);
}